// Round 7
// baseline (3507.157 us; speedup 1.0000x reference)
//
#include <hip/hip_runtime.h>
#include <hip/hip_bf16.h>

// GRU encoder: B=64, T=100, E=512, U=512.
// d_out = FLOAT32: output [B,T,U] then states [2,B,U].
// Scan exchange: tag-in-data 8B records via LLC (sc0 sc1), no flags/drains.
// ws footprint unchanged (~131 MB); pk buffers live in dead regions.

#define TT 100

using f32x4 = __attribute__((ext_vector_type(4))) float;
using s16x8 = __attribute__((ext_vector_type(8))) short;
using u32x2 = __attribute__((ext_vector_type(2))) unsigned;
using u32x4 = __attribute__((ext_vector_type(4))) unsigned;
typedef unsigned long long u64;

__device__ __forceinline__ unsigned short f2bfu(float x) {
  __hip_bfloat16 b = __float2bfloat16(x);
  unsigned short u;
  __builtin_memcpy(&u, &b, sizeof(u));
  return u;
}
__device__ __forceinline__ float bfu2f(unsigned short u) {
  __hip_bfloat16 b;
  __builtin_memcpy(&b, &u, sizeof(b));
  return __bfloat162float(b);
}
__device__ __forceinline__ float sigm(float x) {
  x = fminf(fmaxf(x, -30.f), 30.f);
  return 1.f / (1.f + __expf(-x));
}
__device__ __forceinline__ float tanh_fast(float x) {
  x = fminf(fmaxf(x, -15.f), 15.f);
  float e = __expf(-2.f * x);
  return (1.f - e) / (1.f + e);
}
__device__ __forceinline__ void vm_drain() {
  asm volatile("s_waitcnt vmcnt(0)" ::: "memory");
}

// ---------------------------------------------------------------- embedding
__global__ __launch_bounds__(128) void embed_kernel(const int* __restrict__ x,
                                                    const float* __restrict__ emb,
                                                    float* __restrict__ xs) {
  const int row = blockIdx.x;            // row = t*64 + b  (time-major)
  const int t = row >> 6, b = row & 63;
  const int idx = x[b * TT + t];
  const f32x4* s = (const f32x4*)(emb + (size_t)idx * 512);
  f32x4* d = (f32x4*)(xs + (size_t)row * 512);
  d[threadIdx.x] = s[threadIdx.x];
}

// ------------------------------------------------- pack recurrent weights
// B-fragment layout for mfma_f32_16x16x32_bf16, split into bf16 hi/lo.
// [nt 0..95][kt 0..15][lane 0..63][elem 0..7]; nt 0..63 = gate cols,
// nt 64..95 = candidate cols. k = h-part rows (ein + k).
__global__ __launch_bounds__(256) void pack_w_kernel(const float* __restrict__ Wg,
                                                     const float* __restrict__ Wc,
                                                     int ldg, int ldc, int ein,
                                                     unsigned short* __restrict__ hi,
                                                     unsigned short* __restrict__ lo) {
  const int gg = blockIdx.x * 256 + threadIdx.x;
  if (gg >= 96 * 16 * 64) return;
  const int lane = gg & 63;
  const int pair = gg >> 6;
  const int kt = pair & 15;
  const int nt = pair >> 4;
  const int kg = lane >> 4;
  const int nl = lane & 15;
  const size_t off = (size_t)gg * 8;
  for (int i = 0; i < 8; ++i) {
    const int k = kt * 32 + kg * 8 + i;
    float v = (nt < 64) ? Wg[(size_t)(ein + k) * ldg + nt * 16 + nl]
                        : Wc[(size_t)(ein + k) * ldc + (nt - 64) * 16 + nl];
    unsigned short h = f2bfu(v);
    hi[off + i] = h;
    lo[off + i] = f2bfu(v - bfu2f(h));
  }
}

// ------------------------------------------------------- fp32 input-proj GEMM
struct GemmSegs {
  int seg_end[4];
  const float* w[4];
  int ldw[4];
  const float* bias[4];
  float* c[4];
  int col0[4];
};

__global__ __launch_bounds__(256) void gemm_f32_kernel(const float* __restrict__ A,
                                                       int lda, int K, GemmSegs segs) {
  __shared__ float As[16][132];
  __shared__ float Bs[16][132];
  const int tid = threadIdx.x;
  const int bm = blockIdx.x, bn = blockIdx.y;
  const int n0 = bn * 128;
  int s = 0;
  while (n0 >= segs.seg_end[s]) ++s;
  const int segst = s ? segs.seg_end[s - 1] : 0;
  const float* W = segs.w[s];
  const int ldw = segs.ldw[s];
  const float* bias = segs.bias[s] + (n0 - segst);
  float* C = segs.c[s];
  const int ccol = segs.col0[s] + (n0 - segst);
  const int wn0 = n0 - segst;

  const int alr = tid >> 1, alc = (tid & 1) * 8;
  const int blr = tid >> 4, blc = (tid & 15) * 8;
  const int tm = tid >> 4, tn = tid & 15;

  float acc[8][8] = {};
  const float* Arow = A + (size_t)(bm * 128 + alr) * lda + alc;
  const float* Wrow = W + (size_t)blr * ldw + wn0 + blc;

  for (int k0 = 0; k0 < K; k0 += 16) {
    f32x4 a0 = *(const f32x4*)(Arow + k0);
    f32x4 a1 = *(const f32x4*)(Arow + k0 + 4);
    f32x4 b0 = *(const f32x4*)(Wrow + (size_t)k0 * ldw);
    f32x4 b1 = *(const f32x4*)(Wrow + (size_t)k0 * ldw + 4);
#pragma unroll
    for (int i = 0; i < 4; ++i) {
      As[alc + i][alr] = a0[i];
      As[alc + 4 + i][alr] = a1[i];
    }
    *(f32x4*)&Bs[blr][blc] = b0;
    *(f32x4*)&Bs[blr][blc + 4] = b1;
    __syncthreads();
#pragma unroll
    for (int kk = 0; kk < 16; ++kk) {
      f32x4 xa = *(const f32x4*)&As[kk][tm * 4];
      f32x4 xb = *(const f32x4*)&As[kk][64 + tm * 4];
      f32x4 ya = *(const f32x4*)&Bs[kk][tn * 4];
      f32x4 yb = *(const f32x4*)&Bs[kk][64 + tn * 4];
#pragma unroll
      for (int i = 0; i < 4; ++i)
#pragma unroll
        for (int j = 0; j < 4; ++j) {
          acc[i][j] += xa[i] * ya[j];
          acc[i][j + 4] += xa[i] * yb[j];
          acc[i + 4][j] += xb[i] * ya[j];
          acc[i + 4][j + 4] += xb[i] * yb[j];
        }
    }
    __syncthreads();
  }
  float bv[8];
#pragma unroll
  for (int j = 0; j < 4; ++j) {
    bv[j] = bias[tn * 4 + j];
    bv[j + 4] = bias[64 + tn * 4 + j];
  }
#pragma unroll
  for (int i = 0; i < 8; ++i) {
    const int row = bm * 128 + ((i < 4) ? (tm * 4 + i) : (64 + tm * 4 + i - 4));
    float* cp = C + (size_t)row * 1536 + ccol;
    f32x4 v0, v1;
#pragma unroll
    for (int j = 0; j < 4; ++j) {
      v0[j] = acc[i][j] + bv[j];
      v1[j] = acc[i][j + 4] + bv[j + 4];
    }
    *(f32x4*)(cp + tn * 4) = v0;
    *(f32x4*)(cp + 64 + tn * 4) = v1;
  }
}

// ------------------------------------------------------------- GRU scan
// 8 groups x 32 WGs; WG owns hidden cols [wg*16, wg*16+16). Exchange records:
// u64 { value = hi|lo<<16, tag = 2t+1 (r*h) / 2t+2 (h') } stored sc0/sc1.
// Consumers spin-load their slice and check embedded tags (== match).
template <int NB>
__global__ __launch_bounds__(256, 1) void gru_scan_kernel(
    const float* __restrict__ gxF, const float* __restrict__ gxB,
    const unsigned short* __restrict__ wHiF, const unsigned short* __restrict__ wLoF,
    const unsigned short* __restrict__ wHiB, const unsigned short* __restrict__ wLoB,
    u64* __restrict__ rPk, u64* __restrict__ hPk,
    float* __restrict__ yout, int yld,
    float* __restrict__ outb,
    float* __restrict__ stout) {
  __shared__ unsigned short wHi_s[3 * 8192];   // 48KB: [r|u|c] tiles
  __shared__ unsigned short wLo_s[3 * 8192];   // 48KB
  __shared__ unsigned short hHi_s[8192];       // 16KB (h, then rh), swizzled
  __shared__ unsigned short hLo_s[8192];       // 16KB
  __shared__ float scr[4][16][17];             // r / cand partials
  __shared__ float scr2[4][16][17];            // u partials

  const int tid = threadIdx.x;
  const int lane = tid & 63;
  const int wv = tid >> 6;
  const int bid = blockIdx.x;
  const int g = bid & 7;
  const int wg = bid >> 3;
  const int hs = wg << 4;

  int dir = 0, b0;
  const float* gx;
  const unsigned short *wph, *wpl;
  if (NB == 16) {
    dir = g & 1;
    b0 = (g >> 1) << 4;
    gx = dir ? gxB : gxF;
    wph = dir ? wHiB : wHiF;
    wpl = dir ? wLoB : wLoF;
  } else {
    b0 = g * NB;
    gx = gxF;
    wph = wHiF;
    wpl = wLoF;
  }

  // stationary weight fragments -> LDS
  {
    const int nt0[3] = {wg, 32 + wg, 64 + wg};
    for (int c = 0; c < 3; ++c) {
      const unsigned short* sH = wph + (size_t)nt0[c] * 8192;
      const unsigned short* sL = wpl + (size_t)nt0[c] * 8192;
      unsigned short* dH = wHi_s + c * 8192;
      unsigned short* dL = wLo_s + c * 8192;
#pragma unroll
      for (int it = 0; it < 4; ++it) {
        const int o = (it * 256 + tid) * 8;
        *(s16x8*)(dH + o) = *(const s16x8*)(sH + o);
        *(s16x8*)(dL + o) = *(const s16x8*)(sL + o);
      }
    }
  }
  {  // h(0) = 0
    s16x8 z = {0, 0, 0, 0, 0, 0, 0, 0};
#pragma unroll
    for (int it = 0; it < 4; ++it) {
      const int o = (it * 256 + tid) * 8;
      *(s16x8*)(hHi_s + o) = z;
      *(s16x8*)(hLo_s + o) = z;
    }
  }
  __syncthreads();

  // MFMA lane constants
  const int fm = lane & 15;
  const int fkg = lane >> 4;
  const int arow = fm * 512;
  const int asw = (fm & 7) << 3;
  const int akof = fkg * 8;

  // owner mapping: batch = tid>>4, col = tid&15
  const int ob = tid >> 4, oj = tid & 15;
  const bool own = (ob < NB);
  const int ui = ob * 512 + ((hs + oj) ^ ((ob & 7) << 3));

  const size_t tileo = (size_t)g * 8192;

  auto mfma_tile = [&](int cidx, float (*dst)[16][17]) {
    f32x4 acc0 = {0.f, 0.f, 0.f, 0.f}, acc1 = {0.f, 0.f, 0.f, 0.f};
    const int ktb = wv * 4;
#pragma unroll
    for (int q = 0; q < 4; ++q) {
      const int kt = ktb + q;
      const int ao = arow + ((kt * 32 + akof) ^ asw);
      s16x8 ah = *(const s16x8*)(hHi_s + ao);
      s16x8 al = *(const s16x8*)(hLo_s + ao);
      const int wo = ((cidx * 16 + kt) * 64 + lane) * 8;
      s16x8 bh = *(const s16x8*)(wHi_s + wo);
      s16x8 bl = *(const s16x8*)(wLo_s + wo);
      if (q & 1) {
        acc1 = __builtin_amdgcn_mfma_f32_16x16x32_bf16(ah, bh, acc1, 0, 0, 0);
        acc1 = __builtin_amdgcn_mfma_f32_16x16x32_bf16(ah, bl, acc1, 0, 0, 0);
        acc1 = __builtin_amdgcn_mfma_f32_16x16x32_bf16(al, bh, acc1, 0, 0, 0);
      } else {
        acc0 = __builtin_amdgcn_mfma_f32_16x16x32_bf16(ah, bh, acc0, 0, 0, 0);
        acc0 = __builtin_amdgcn_mfma_f32_16x16x32_bf16(ah, bl, acc0, 0, 0, 0);
        acc0 = __builtin_amdgcn_mfma_f32_16x16x32_bf16(al, bh, acc0, 0, 0, 0);
      }
    }
#pragma unroll
    for (int j = 0; j < 4; ++j) dst[wv][fkg * 4 + j][fm] = acc0[j] + acc1[j];
  };

  // spin-load a tile's slice, verify embedded tags, unpack to LDS hi/lo.
  auto spin_load = [&](const u64* pk, unsigned tag) {
    const int ept = NB * 2;                 // entries per thread
#pragma unroll
    for (int c = 0; c < NB / 8; ++c) {      // 16 entries per chunk
      const int eb = tid * ept + c * 16;
      const u64* src = pk + tileo + eb;
      u32x4 d[8];
      while (true) {
#pragma unroll
        for (int i = 0; i < 8; ++i)
          asm volatile("global_load_dwordx4 %0, %1, off sc0 sc1"
                       : "=v"(d[i]) : "v"(src + 2 * i) : "memory");
        vm_drain();
        bool ok = true;
#pragma unroll
        for (int i = 0; i < 8; ++i) ok &= (d[i][1] == tag) & (d[i][3] == tag);
        if (ok) break;
        __builtin_amdgcn_s_sleep(2);
      }
      unsigned hd[8], ld_[8];
#pragma unroll
      for (int k = 0; k < 8; ++k) {
        const unsigned va = d[k >> 2][(k & 3) ? ((k & 3) == 1 ? 2 : 0) : 0];
        (void)va;
      }
      // entry j value dword: v[j] = d[j>>1][(j&1)*2]
#pragma unroll
      for (int k = 0; k < 8; ++k) {
        const unsigned v0 = d[(2 * k) >> 1][0];        // j=2k  -> d[k][0]
        const unsigned v1 = d[(2 * k + 1) >> 1][2];    // j=2k+1-> d[k][2]
        hd[k] = (v0 & 0xffffu) | (v1 << 16);
        ld_[k] = (v0 >> 16) | (v1 & 0xffff0000u);
      }
      u32x4 hA, hB, lA, lB;
#pragma unroll
      for (int k = 0; k < 4; ++k) { hA[k] = hd[k]; hB[k] = hd[k + 4]; lA[k] = ld_[k]; lB[k] = ld_[k + 4]; }
      *(u32x4*)(hHi_s + eb) = hA;
      *(u32x4*)(hHi_s + eb + 8) = hB;
      *(u32x4*)(hLo_s + eb) = lA;
      *(u32x4*)(hLo_s + eb + 8) = lB;
    }
  };

  // gx for step 0
  float gxr = 0.f, gxu = 0.f, gxc = 0.f;
  if (own) {
    const float* row = gx + ((size_t)(dir ? TT - 1 : 0) * 64 + b0 + ob) * 1536 + hs + oj;
    gxr = row[0]; gxu = row[512]; gxc = row[1024];
  }

  float hv = 0.f;
  for (int t = 0; t < TT; ++t) {
    const int tg = dir ? (TT - 1 - t) : t;

    // ---- G1r: r-gate MFMAs ----
    mfma_tile(0, scr);
    __syncthreads();

    // ---- S1: sigmoid(r), store r*h records (tag 2t+1) ----
    if (own) {
      float rpre = scr[0][ob][oj] + scr[1][ob][oj] + scr[2][ob][oj] + scr[3][ob][oj] + gxr;
      float sg = sigm(rpre);
      hv = bfu2f(hHi_s[ui]) + bfu2f(hLo_s[ui]);
      float rh = sg * hv;
      unsigned short hh_ = f2bfu(rh);
      unsigned short ll_ = f2bfu(rh - bfu2f(hh_));
      u32x2 e;
      e[0] = (unsigned)hh_ | ((unsigned)ll_ << 16);
      e[1] = (unsigned)(2 * t + 1);
      asm volatile("global_store_dwordx2 %0, %1, off sc0 sc1"
                   :: "v"(rPk + tileo + ui), "v"(e) : "memory");
    }

    // ---- G1u: u-gate MFMAs (cover rh commit latency) ----
    mfma_tile(1, scr2);

    // ---- prefetch next step's gx ----
    float ngxr = 0.f, ngxu = 0.f, ngxc = 0.f;
    if (own && t + 1 < TT) {
      const int tgn = dir ? (TT - 2 - t) : (t + 1);
      const float* row = gx + ((size_t)tgn * 64 + b0 + ob) * 1536 + hs + oj;
      ngxr = row[0]; ngxu = row[512]; ngxc = row[1024];
    }
    __syncthreads();     // T readers (G1u) done; scr2 complete

    // ---- exchange 1: r*h ----
    spin_load(rPk, (unsigned)(2 * t + 1));
    __syncthreads();

    // ---- G2: candidate MFMAs ----
    mfma_tile(2, scr);
    __syncthreads();

    // ---- S2: u, tanh, h update, store h' records (tag 2t+2) ----
    float hn = 0.f;
    if (own) {
      float upre = scr2[0][ob][oj] + scr2[1][ob][oj] + scr2[2][ob][oj] + scr2[3][ob][oj] + gxu;
      float uv = sigm(upre);
      float cpre = scr[0][ob][oj] + scr[1][ob][oj] + scr[2][ob][oj] + scr[3][ob][oj] + gxc;
      float cv = tanh_fast(cpre);
      hn = uv * hv + (1.f - uv) * cv;
    }

    if (t == TT - 1) {
      if (own) {
        if (yout) {
          const int ycol = (NB == 16) ? (dir * 512 + hs + oj) : (hs + oj);
          yout[((size_t)tg * 64 + (b0 + ob)) * yld + ycol] = hn;
        }
        if (outb) outb[((size_t)(b0 + ob) * TT + t) * 512 + hs + oj] = hn;
        if (stout) stout[(size_t)(b0 + ob) * 512 + hs + oj] = hn;
      }
      break;
    }

    if (own) {
      unsigned short hh_ = f2bfu(hn);
      unsigned short ll_ = f2bfu(hn - bfu2f(hh_));
      u32x2 e;
      e[0] = (unsigned)hh_ | ((unsigned)ll_ << 16);
      e[1] = (unsigned)(2 * t + 2);
      asm volatile("global_store_dwordx2 %0, %1, off sc0 sc1"
                   :: "v"(hPk + tileo + ui), "v"(e) : "memory");
      // y-writes cover h' commit latency
      if (yout) {
        const int ycol = (NB == 16) ? (dir * 512 + hs + oj) : (hs + oj);
        yout[((size_t)tg * 64 + (b0 + ob)) * yld + ycol] = hn;
      }
      if (outb) outb[((size_t)(b0 + ob) * TT + t) * 512 + hs + oj] = hn;
    }
    gxr = ngxr; gxu = ngxu; gxc = ngxc;

    // ---- exchange 2: h' ----
    spin_load(hPk, (unsigned)(2 * t + 2));
    __syncthreads();
  }
}

// ---------------------------------------------------------------- launcher
extern "C" void kernel_launch(void* const* d_in, const int* in_sizes, int n_in,
                              void* d_out, int out_size, void* d_ws, size_t ws_size,
                              hipStream_t stream) {
  (void)in_sizes; (void)n_in; (void)out_size; (void)ws_size;
  const int* x = (const int*)d_in[0];
  const float* emb = (const float*)d_in[1];
  const float* WgFw = (const float*)d_in[2];
  const float* bgFw = (const float*)d_in[3];
  const float* WcFw = (const float*)d_in[4];
  const float* bcFw = (const float*)d_in[5];
  const float* WgBw = (const float*)d_in[6];
  const float* bgBw = (const float*)d_in[7];
  const float* WcBw = (const float*)d_in[8];
  const float* bcBw = (const float*)d_in[9];
  const float* WgU1 = (const float*)d_in[10];
  const float* bgU1 = (const float*)d_in[11];
  const float* WcU1 = (const float*)d_in[12];
  const float* bcU1 = (const float*)d_in[13];
  const float* WgU2 = (const float*)d_in[14];
  const float* bgU2 = (const float*)d_in[15];
  const float* WcU2 = (const float*)d_in[16];
  const float* bcU2 = (const float*)d_in[17];

  char* ws = (char*)d_ws;
  float* xs = (float*)(ws + 0);                      // 13,107,200 B
  float* bufA = (float*)(ws + 13107200);             // 39,321,600 B
  float* bufB = (float*)(ws + 52428800);             // 39,321,600 B
  float* ycat = (float*)(ws + 91750400);             // 26,214,400 B
  unsigned short* wp = (unsigned short*)(ws + 117964800);  // 12,582,912 B
  float* y1 = xs;
  float* gxU1 = bufA;
  float* gxU2 = bufB;

  // Exchange record buffers in dead regions (memset to tag=0 before use):
  // bidir scan: xs[0..1MB) is dead (embed consumed by GEMM; y1 written later).
  // u1/u2 scans: ycat[0..2MB) is dead (consumed by the preceding GEMM).
  u64* pk0r = (u64*)xs;                 u64* pk0h = pk0r + 65536;
  u64* pk1r = (u64*)ycat;               u64* pk1h = pk1r + 65536;
  u64* pk2r = (u64*)((char*)ycat + (1 << 20)); u64* pk2h = pk2r + 65536;

  unsigned short* wpFwHi = wp + 0 * 786432;
  unsigned short* wpFwLo = wp + 1 * 786432;
  unsigned short* wpBwHi = wp + 2 * 786432;
  unsigned short* wpBwLo = wp + 3 * 786432;
  unsigned short* wpU1Hi = wp + 4 * 786432;
  unsigned short* wpU1Lo = wp + 5 * 786432;
  unsigned short* wpU2Hi = wp + 6 * 786432;
  unsigned short* wpU2Lo = wp + 7 * 786432;

  float* out = (float*)d_out;
  float* st1 = out + (size_t)64 * TT * 512;
  float* st2 = st1 + 64 * 512;

  embed_kernel<<<6400, 128, 0, stream>>>(x, emb, xs);
  pack_w_kernel<<<384, 256, 0, stream>>>(WgFw, WcFw, 1024, 512, 512, wpFwHi, wpFwLo);
  pack_w_kernel<<<384, 256, 0, stream>>>(WgBw, WcBw, 1024, 512, 512, wpBwHi, wpBwLo);
  pack_w_kernel<<<384, 256, 0, stream>>>(WgU1, WcU1, 1024, 512, 1024, wpU1Hi, wpU1Lo);
  pack_w_kernel<<<384, 256, 0, stream>>>(WgU2, WcU2, 1024, 512, 512, wpU2Hi, wpU2Lo);

  {  // bidirectional input projections
    GemmSegs sg;
    sg.seg_end[0] = 1024; sg.seg_end[1] = 1536; sg.seg_end[2] = 2560; sg.seg_end[3] = 3072;
    sg.w[0] = WgFw; sg.w[1] = WcFw; sg.w[2] = WgBw; sg.w[3] = WcBw;
    sg.ldw[0] = 1024; sg.ldw[1] = 512; sg.ldw[2] = 1024; sg.ldw[3] = 512;
    sg.bias[0] = bgFw; sg.bias[1] = bcFw; sg.bias[2] = bgBw; sg.bias[3] = bcBw;
    sg.c[0] = bufA; sg.c[1] = bufA; sg.c[2] = bufB; sg.c[3] = bufB;
    sg.col0[0] = 0; sg.col0[1] = 1024; sg.col0[2] = 0; sg.col0[3] = 1024;
    gemm_f32_kernel<<<dim3(50, 24), 256, 0, stream>>>(xs, 512, 512, sg);
  }
  hipMemsetAsync(pk0r, 0, 1 << 20, stream);   // tag=0 (xs dead after GEMM)
  {  // bidirectional scan
    const float *a0 = bufA, *a1 = bufB;
    const unsigned short *w0 = wpFwHi, *w1 = wpFwLo, *w2 = wpBwHi, *w3 = wpBwLo;
    u64 *r0 = pk0r, *h0 = pk0h;
    float* yo = ycat; int yld = 1024;
    float *on = nullptr, *sn = nullptr;
    void* args[] = {&a0, &a1, &w0, &w1, &w2, &w3, &r0, &h0, &yo, &yld, &on, &sn};
    hipLaunchCooperativeKernel((const void*)gru_scan_kernel<16>, dim3(256), dim3(256),
                               args, 0, stream);
  }
  {  // u1 input projections
    GemmSegs sg;
    sg.seg_end[0] = 1024; sg.seg_end[1] = 1536; sg.seg_end[2] = 1 << 30; sg.seg_end[3] = 1 << 30;
    sg.w[0] = WgU1; sg.w[1] = WcU1; sg.w[2] = nullptr; sg.w[3] = nullptr;
    sg.ldw[0] = 1024; sg.ldw[1] = 512; sg.ldw[2] = 0; sg.ldw[3] = 0;
    sg.bias[0] = bgU1; sg.bias[1] = bcU1; sg.bias[2] = nullptr; sg.bias[3] = nullptr;
    sg.c[0] = gxU1; sg.c[1] = gxU1; sg.c[2] = nullptr; sg.c[3] = nullptr;
    sg.col0[0] = 0; sg.col0[1] = 1024; sg.col0[2] = 0; sg.col0[3] = 0;
    gemm_f32_kernel<<<dim3(50, 12), 256, 0, stream>>>(ycat, 1024, 1024, sg);
  }
  hipMemsetAsync(pk1r, 0, 1 << 20, stream);   // ycat dead after u1 GEMM
  {  // u1 scan
    const float *a0 = gxU1, *a1 = nullptr;
    const unsigned short *w0 = wpU1Hi, *w1 = wpU1Lo, *w2 = nullptr, *w3 = nullptr;
    u64 *r0 = pk1r, *h0 = pk1h;
    float* yo = y1; int yld = 512;
    float *on = nullptr, *sn = st1;
    void* args[] = {&a0, &a1, &w0, &w1, &w2, &w3, &r0, &h0, &yo, &yld, &on, &sn};
    hipLaunchCooperativeKernel((const void*)gru_scan_kernel<8>, dim3(256), dim3(256),
                               args, 0, stream);
  }
  {  // u2 input projections
    GemmSegs sg;
    sg.seg_end[0] = 1024; sg.seg_end[1] = 1536; sg.seg_end[2] = 1 << 30; sg.seg_end[3] = 1 << 30;
    sg.w[0] = WgU2; sg.w[1] = WcU2; sg.w[2] = nullptr; sg.w[3] = nullptr;
    sg.ldw[0] = 1024; sg.ldw[1] = 512; sg.ldw[2] = 0; sg.ldw[3] = 0;
    sg.bias[0] = bgU2; sg.bias[1] = bcU2; sg.bias[2] = nullptr; sg.bias[3] = nullptr;
    sg.c[0] = gxU2; sg.c[1] = gxU2; sg.c[2] = nullptr; sg.c[3] = nullptr;
    sg.col0[0] = 0; sg.col0[1] = 1024; sg.col0[2] = 0; sg.col0[3] = 0;
    gemm_f32_kernel<<<dim3(50, 12), 256, 0, stream>>>(y1, 512, 512, sg);
  }
  hipMemsetAsync(pk2r, 0, 1 << 20, stream);   // ycat dead after u2 GEMM
  {  // u2 scan -> d_out (f32) + state2
    const float *a0 = gxU2, *a1 = nullptr;
    const unsigned short *w0 = wpU2Hi, *w1 = wpU2Lo, *w2 = nullptr, *w3 = nullptr;
    u64 *r0 = pk2r, *h0 = pk2h;
    float* yo = nullptr; int yld = 0;
    float *on = out, *sn = st2;
    void* args[] = {&a0, &a1, &w0, &w1, &w2, &w3, &r0, &h0, &yo, &yld, &on, &sn};
    hipLaunchCooperativeKernel((const void*)gru_scan_kernel<8>, dim3(256), dim3(256),
                               args, 0, stream);
  }
}

// Round 8
// 1783.026 us; speedup vs baseline: 1.9670x; 1.9670x over previous
//
#include <hip/hip_runtime.h>
#include <hip/hip_bf16.h>

// GRU encoder: B=64, T=100, E=512, U=512.
// d_out = FLOAT32: output [B,T,U] then states [2,B,U].
// Scan = round-6 proven structure (sc1 exchange + monotonic slot flags).
// Input projections = split-bf16 MFMA GEMM; weights packed full-K fragments;
// activations carried as bf16 hi/lo planes. ws <= ~127.5 MB.

#define TT 100

using f32x4 = __attribute__((ext_vector_type(4))) float;
using s16x8 = __attribute__((ext_vector_type(8))) short;

__device__ __forceinline__ unsigned short f2bfu(float x) {
  __hip_bfloat16 b = __float2bfloat16(x);
  unsigned short u;
  __builtin_memcpy(&u, &b, sizeof(u));
  return u;
}
__device__ __forceinline__ float bfu2f(unsigned short u) {
  __hip_bfloat16 b;
  __builtin_memcpy(&b, &u, sizeof(b));
  return __bfloat162float(b);
}
__device__ __forceinline__ float sigm(float x) {
  x = fminf(fmaxf(x, -30.f), 30.f);
  return 1.f / (1.f + __expf(-x));
}
__device__ __forceinline__ float tanh_fast(float x) {
  x = fminf(fmaxf(x, -15.f), 15.f);
  float e = __expf(-2.f * x);
  return (1.f - e) / (1.f + e);
}

// ---- LLC-coherent (bypass L1/L2) access helpers ----
__device__ __forceinline__ s16x8 sc1_load_b128(const void* p) {
  s16x8 v;
  asm volatile("global_load_dwordx4 %0, %1, off sc0 sc1" : "=v"(v) : "v"(p) : "memory");
  return v;
}
__device__ __forceinline__ void sc1_store_b16(void* p, unsigned v) {
  asm volatile("global_store_short %0, %1, off sc0 sc1" :: "v"(p), "v"(v) : "memory");
}
__device__ __forceinline__ void vm_drain() {
  asm volatile("s_waitcnt vmcnt(0)" ::: "memory");
}

// ------------------------------------------------- pack weights (full K)
// Fragment layout [nt 0..95][kt 0..ktTot-1][lane 0..63][elem 0..7], hi/lo.
// nt<64 -> Wg col nt*16+(lane&15); nt>=64 -> Wc col (nt-64)*16+(lane&15).
// k = kt*32 + (lane>>4)*8 + elem  (covers x-part AND h-part rows).
__global__ __launch_bounds__(256) void pack_w_kernel(const float* __restrict__ Wg,
                                                     const float* __restrict__ Wc,
                                                     int ldg, int ldc, int ktTot,
                                                     unsigned short* __restrict__ hi,
                                                     unsigned short* __restrict__ lo) {
  const int gg = blockIdx.x * 256 + threadIdx.x;
  if (gg >= 96 * ktTot * 64) return;
  const int lane = gg & 63;
  const int pair = gg >> 6;
  const int kt = pair % ktTot;
  const int nt = pair / ktTot;
  const int kg = lane >> 4;
  const int nl = lane & 15;
  const size_t off = (size_t)gg * 8;
  for (int i = 0; i < 8; ++i) {
    const int k = kt * 32 + kg * 8 + i;
    float v = (nt < 64) ? Wg[(size_t)k * ldg + nt * 16 + nl]
                        : Wc[(size_t)k * ldc + (nt - 64) * 16 + nl];
    unsigned short h = f2bfu(v);
    hi[off + i] = h;
    lo[off + i] = f2bfu(v - bfu2f(h));
  }
}

// --------------------------------------------- split-bf16 MFMA input GEMM
// C[6400][1536] = A[6400][K] @ W[K][1536] + bias, K = ktX*32.
// ASRC=0: A = embedding gather (fp32 -> hi/lo). ASRC=1: A = hi/lo planes.
// B read from packed fragments (kt 0..ktX-1). 128x128 tile, 4 waves.
template <int ASRC>
__global__ __launch_bounds__(256) void gemm_mfma(
    const int* __restrict__ xtok, const float* __restrict__ emb,
    const unsigned short* __restrict__ aHi, const unsigned short* __restrict__ aLo, int lda,
    const unsigned short* __restrict__ bHi, const unsigned short* __restrict__ bLo,
    int ktTot, int ktX,
    const float* __restrict__ bg, const float* __restrict__ bc,
    float* __restrict__ C) {
  __shared__ unsigned short Ah[128 * 40];   // pad-40 stride: conflict-free frag reads
  __shared__ unsigned short Al[128 * 40];

  const int tid = threadIdx.x;
  const int lane = tid & 63;
  const int w = tid >> 6;
  const int bm = blockIdx.x, bn = blockIdx.y;
  const int fm = lane & 15, fkg = lane >> 4;

  const int arow = tid >> 1;            // staged row 0..127
  const int koff = (tid & 1) * 16;      // k offset within 32
  const int rowg = bm * 128 + arow;
  int embIdx = 0;
  if (ASRC == 0) {
    const int t_ = rowg >> 6, b_ = rowg & 63;   // row = t*64 + b
    embIdx = xtok[b_ * TT + t_];
  }

  f32x4 acc[2][8];
#pragma unroll
  for (int rt = 0; rt < 2; ++rt)
#pragma unroll
    for (int ni = 0; ni < 8; ++ni) acc[rt][ni] = (f32x4){0.f, 0.f, 0.f, 0.f};

  for (int kt = 0; kt < ktX; ++kt) {
    __syncthreads();
    if (ASRC == 0) {
      const float* src = emb + (size_t)embIdx * 512 + kt * 32 + koff;
      s16x8 h0, h1, l0, l1;
#pragma unroll
      for (int c = 0; c < 2; ++c) {
        f32x4 va = *(const f32x4*)(src + c * 8);
        f32x4 vb = *(const f32x4*)(src + c * 8 + 4);
        s16x8 hh, ll;
#pragma unroll
        for (int j = 0; j < 4; ++j) {
          unsigned short h = f2bfu(va[j]);
          hh[j] = (short)h; ll[j] = (short)f2bfu(va[j] - bfu2f(h));
          unsigned short h2 = f2bfu(vb[j]);
          hh[j + 4] = (short)h2; ll[j + 4] = (short)f2bfu(vb[j] - bfu2f(h2));
        }
        if (c == 0) { h0 = hh; l0 = ll; } else { h1 = hh; l1 = ll; }
      }
      *(s16x8*)(Ah + arow * 40 + koff) = h0;
      *(s16x8*)(Ah + arow * 40 + koff + 8) = h1;
      *(s16x8*)(Al + arow * 40 + koff) = l0;
      *(s16x8*)(Al + arow * 40 + koff + 8) = l1;
    } else {
      const size_t so = (size_t)rowg * lda + kt * 32 + koff;
      s16x8 h0 = *(const s16x8*)(aHi + so);
      s16x8 h1 = *(const s16x8*)(aHi + so + 8);
      s16x8 l0 = *(const s16x8*)(aLo + so);
      s16x8 l1 = *(const s16x8*)(aLo + so + 8);
      *(s16x8*)(Ah + arow * 40 + koff) = h0;
      *(s16x8*)(Ah + arow * 40 + koff + 8) = h1;
      *(s16x8*)(Al + arow * 40 + koff) = l0;
      *(s16x8*)(Al + arow * 40 + koff + 8) = l1;
    }
    __syncthreads();

    s16x8 ah[2], al[2];
#pragma unroll
    for (int rt = 0; rt < 2; ++rt) {
      const int m = w * 32 + rt * 16 + fm;
      ah[rt] = *(const s16x8*)(Ah + m * 40 + fkg * 8);
      al[rt] = *(const s16x8*)(Al + m * 40 + fkg * 8);
    }
#pragma unroll
    for (int ni = 0; ni < 8; ++ni) {
      const int nt = bn * 8 + ni;
      const size_t bo = ((size_t)nt * ktTot + kt) * 512 + lane * 8;
      s16x8 bh = *(const s16x8*)(bHi + bo);
      s16x8 bl = *(const s16x8*)(bLo + bo);
#pragma unroll
      for (int rt = 0; rt < 2; ++rt) {
        acc[rt][ni] = __builtin_amdgcn_mfma_f32_16x16x32_bf16(ah[rt], bh, acc[rt][ni], 0, 0, 0);
        acc[rt][ni] = __builtin_amdgcn_mfma_f32_16x16x32_bf16(ah[rt], bl, acc[rt][ni], 0, 0, 0);
        acc[rt][ni] = __builtin_amdgcn_mfma_f32_16x16x32_bf16(al[rt], bh, acc[rt][ni], 0, 0, 0);
      }
    }
  }

  // epilogue: bias + fp32 store (D: col = lane&15, row = (lane>>4)*4 + j)
#pragma unroll
  for (int ni = 0; ni < 8; ++ni) {
    const int nt = bn * 8 + ni;
    int dcol; float bias;
    if (nt < 64) { dcol = nt * 16 + fm; bias = bg[dcol]; }
    else { dcol = 1024 + (nt - 64) * 16 + fm; bias = bc[(nt - 64) * 16 + fm]; }
#pragma unroll
    for (int rt = 0; rt < 2; ++rt)
#pragma unroll
      for (int j = 0; j < 4; ++j) {
        const int row = bm * 128 + w * 32 + rt * 16 + fkg * 4 + j;
        C[(size_t)row * 1536 + dcol] = acc[rt][ni][j] + bias;
      }
  }
}

// ------------------------------------------------------------- GRU scan
// Round-6 proven structure. Weights staged from full-K pack (kt >= ktH0).
// y emitted as bf16 hi/lo planes (feeds next GEMM) or fp32 outb (final layer).
template <int NB>
__global__ __launch_bounds__(256, 1) void gru_scan_kernel(
    const float* __restrict__ gxF, const float* __restrict__ gxB,
    const unsigned short* __restrict__ wHiF, const unsigned short* __restrict__ wLoF,
    const unsigned short* __restrict__ wHiB, const unsigned short* __restrict__ wLoB,
    int ktTot, int ktH0,
    unsigned short* __restrict__ hHiG, unsigned short* __restrict__ hLoG,
    unsigned short* __restrict__ rHiG, unsigned short* __restrict__ rLoG,
    unsigned* __restrict__ slots,
    unsigned short* __restrict__ yHi, unsigned short* __restrict__ yLo, int yld,
    float* __restrict__ outb,
    float* __restrict__ stout) {
  __shared__ unsigned short wHi_s[3 * 8192];   // 48KB: [r|u|c] h-part tiles
  __shared__ unsigned short wLo_s[3 * 8192];   // 48KB
  __shared__ unsigned short hHi_s[8192];       // 16KB (h, then rh), swizzled
  __shared__ unsigned short hLo_s[8192];       // 16KB
  __shared__ float scr[4][16][17];             // r / cand partials
  __shared__ float scr2[4][16][17];            // u partials

  const int tid = threadIdx.x;
  const int lane = tid & 63;
  const int wv = tid >> 6;
  const int bid = blockIdx.x;
  const int g = bid & 7;
  const int wg = bid >> 3;
  const int hs = wg << 4;

  int dir = 0, b0;
  const float* gx;
  const unsigned short *wph, *wpl;
  if (NB == 16) {
    dir = g & 1;
    b0 = (g >> 1) << 4;
    gx = dir ? gxB : gxF;
    wph = dir ? wHiB : wHiF;
    wpl = dir ? wLoB : wLoF;
  } else {
    b0 = g * NB;
    gx = gxF;
    wph = wHiF;
    wpl = wLoF;
  }

  // stationary weight fragments (h-part) -> LDS
  {
    const int nt0[3] = {wg, 32 + wg, 64 + wg};
    for (int c = 0; c < 3; ++c) {
      const unsigned short* sH = wph + ((size_t)nt0[c] * ktTot + ktH0) * 512;
      const unsigned short* sL = wpl + ((size_t)nt0[c] * ktTot + ktH0) * 512;
      unsigned short* dH = wHi_s + c * 8192;
      unsigned short* dL = wLo_s + c * 8192;
#pragma unroll
      for (int it = 0; it < 4; ++it) {
        const int o = (it * 256 + tid) * 8;
        *(s16x8*)(dH + o) = *(const s16x8*)(sH + o);
        *(s16x8*)(dL + o) = *(const s16x8*)(sL + o);
      }
    }
  }
  {  // h(0) = 0
    s16x8 z = {0, 0, 0, 0, 0, 0, 0, 0};
#pragma unroll
    for (int it = 0; it < 4; ++it) {
      const int o = (it * 256 + tid) * 8;
      *(s16x8*)(hHi_s + o) = z;
      *(s16x8*)(hLo_s + o) = z;
    }
  }
  __syncthreads();

  unsigned* gslots = slots + g * 32;

  // MFMA lane constants
  const int fm = lane & 15;
  const int fkg = lane >> 4;
  const int arow = fm * 512;
  const int asw = (fm & 7) << 3;
  const int akof = fkg * 8;

  // owner mapping: batch = tid>>4, col = tid&15
  const int ob = tid >> 4, oj = tid & 15;
  const bool own = (ob < NB);
  const int ui = ob * 512 + ((hs + oj) ^ ((ob & 7) << 3));

  const size_t tileo = (size_t)g * 8192;

  auto mfma_tile = [&](int cidx, float (*dst)[16][17]) {
    f32x4 acc0 = {0.f, 0.f, 0.f, 0.f}, acc1 = {0.f, 0.f, 0.f, 0.f};
    const int ktb = wv * 4;
#pragma unroll
    for (int q = 0; q < 4; ++q) {
      const int kt = ktb + q;
      const int ao = arow + ((kt * 32 + akof) ^ asw);
      s16x8 ah = *(const s16x8*)(hHi_s + ao);
      s16x8 al = *(const s16x8*)(hLo_s + ao);
      const int wo = ((cidx * 16 + kt) * 64 + lane) * 8;
      s16x8 bh = *(const s16x8*)(wHi_s + wo);
      s16x8 bl = *(const s16x8*)(wLo_s + wo);
      if (q & 1) {
        acc1 = __builtin_amdgcn_mfma_f32_16x16x32_bf16(ah, bh, acc1, 0, 0, 0);
        acc1 = __builtin_amdgcn_mfma_f32_16x16x32_bf16(ah, bl, acc1, 0, 0, 0);
        acc1 = __builtin_amdgcn_mfma_f32_16x16x32_bf16(al, bh, acc1, 0, 0, 0);
      } else {
        acc0 = __builtin_amdgcn_mfma_f32_16x16x32_bf16(ah, bh, acc0, 0, 0, 0);
        acc0 = __builtin_amdgcn_mfma_f32_16x16x32_bf16(ah, bl, acc0, 0, 0, 0);
        acc0 = __builtin_amdgcn_mfma_f32_16x16x32_bf16(al, bh, acc0, 0, 0, 0);
      }
    }
#pragma unroll
    for (int j = 0; j < 4; ++j) dst[wv][fkg * 4 + j][fm] = acc0[j] + acc1[j];
  };

  auto load_tile = [&](const unsigned short* SH, const unsigned short* SL) {
    s16x8 th[NB / 4], tl[NB / 4];
#pragma unroll
    for (int it = 0; it < NB / 4; ++it) {
      const int o = (it * 256 + tid) * 8;
      th[it] = sc1_load_b128(SH + tileo + o);
      tl[it] = sc1_load_b128(SL + tileo + o);
    }
    vm_drain();
#pragma unroll
    for (int it = 0; it < NB / 4; ++it) {
      const int o = (it * 256 + tid) * 8;
      *(s16x8*)(hHi_s + o) = th[it];
      *(s16x8*)(hLo_s + o) = tl[it];
    }
  };

  auto poll = [&](unsigned target) {
    if (tid < 32) {
      const unsigned* p = gslots + tid;
      unsigned v;
      do {
        asm volatile("global_load_dword %0, %1, off sc0 sc1\n\ts_waitcnt vmcnt(0)"
                     : "=v"(v) : "v"(p) : "memory");
      } while (!__all(v >= target));
    }
    __syncthreads();
  };

  // gx prefetch for step 0
  float gxr = 0.f, gxu = 0.f, gxc = 0.f;
  if (own) {
    const float* row = gx + ((size_t)(dir ? TT - 1 : 0) * 64 + b0 + ob) * 1536 + hs + oj;
    gxr = row[0]; gxu = row[512]; gxc = row[1024];
  }

  for (int t = 0; t < TT; ++t) {
    const int tg = dir ? (TT - 1 - t) : t;

    // ---- G1r: r-gate MFMAs ----
    mfma_tile(0, scr);
    __syncthreads();

    // ---- S1: sigmoid(r), store r*h (hi/lo) ----
    float hv = 0.f;
    if (own) {
      float rpre = scr[0][ob][oj] + scr[1][ob][oj] + scr[2][ob][oj] + scr[3][ob][oj] + gxr;
      float sg = sigm(rpre);
      hv = bfu2f(hHi_s[ui]) + bfu2f(hLo_s[ui]);
      float rh = sg * hv;
      unsigned short rhh = f2bfu(rh);
      sc1_store_b16(rHiG + tileo + ui, rhh);
      sc1_store_b16(rLoG + tileo + ui, f2bfu(rh - bfu2f(rhh)));
    }
    vm_drain();
    __syncthreads();
    if (tid == 0) {
      unsigned* p = gslots + wg;
      unsigned tv = 2 * t + 1;
      asm volatile("global_store_dword %0, %1, off sc0 sc1" :: "v"(p), "v"(tv) : "memory");
    }

    // ---- G1u: u-gate MFMAs (hide flag propagation) ----
    mfma_tile(1, scr2);

    // ---- prefetch next step's gx ----
    float ngxr = 0.f, ngxu = 0.f, ngxc = 0.f;
    if (own && t + 1 < TT) {
      const int tgn = dir ? (TT - 2 - t) : (t + 1);
      const float* row = gx + ((size_t)tgn * 64 + b0 + ob) * 1536 + hs + oj;
      ngxr = row[0]; ngxu = row[512]; ngxc = row[1024];
    }

    poll(2 * t + 1);
    load_tile(rHiG, rLoG);    // r*h -> LDS (overwrites h)
    __syncthreads();

    // ---- G2: candidate MFMAs ----
    mfma_tile(2, scr);
    __syncthreads();

    // ---- S2: u from scr2, tanh, h update ----
    float hn = 0.f;
    unsigned short hh_ = 0, ll_ = 0;
    if (own) {
      float upre = scr2[0][ob][oj] + scr2[1][ob][oj] + scr2[2][ob][oj] + scr2[3][ob][oj] + gxu;
      float uv = sigm(upre);
      float cpre = scr[0][ob][oj] + scr[1][ob][oj] + scr[2][ob][oj] + scr[3][ob][oj] + gxc;
      float cv = tanh_fast(cpre);
      hn = uv * hv + (1.f - uv) * cv;
      hh_ = f2bfu(hn);
      ll_ = f2bfu(hn - bfu2f(hh_));
    }

    if (t == TT - 1) {
      if (own) {
        if (yHi) {
          const int ycol = (NB == 16) ? (dir * 512 + hs + oj) : (hs + oj);
          const size_t yi = ((size_t)tg * 64 + (b0 + ob)) * yld + ycol;
          yHi[yi] = hh_; yLo[yi] = ll_;
        }
        if (outb) outb[((size_t)(b0 + ob) * TT + t) * 512 + hs + oj] = hn;
        if (stout) stout[(size_t)(b0 + ob) * 512 + hs + oj] = hn;
      }
      break;
    }

    if (own) {
      sc1_store_b16(hHiG + tileo + ui, hh_);
      sc1_store_b16(hLoG + tileo + ui, ll_);
    }
    vm_drain();
    __syncthreads();
    if (tid == 0) {
      unsigned* p = gslots + wg;
      unsigned tv = 2 * t + 2;
      asm volatile("global_store_dword %0, %1, off sc0 sc1" :: "v"(p), "v"(tv) : "memory");
    }

    // ---- y-writes overlap the poll ----
    if (own) {
      if (yHi) {
        const int ycol = (NB == 16) ? (dir * 512 + hs + oj) : (hs + oj);
        const size_t yi = ((size_t)tg * 64 + (b0 + ob)) * yld + ycol;
        yHi[yi] = hh_; yLo[yi] = ll_;
      }
      if (outb) outb[((size_t)(b0 + ob) * TT + t) * 512 + hs + oj] = hn;
    }
    gxr = ngxr; gxu = ngxu; gxc = ngxc;

    poll(2 * t + 2);
    load_tile(hHiG, hLoG);    // h(t) -> LDS
    __syncthreads();
  }
}

// ---------------------------------------------------------------- launcher
extern "C" void kernel_launch(void* const* d_in, const int* in_sizes, int n_in,
                              void* d_out, int out_size, void* d_ws, size_t ws_size,
                              hipStream_t stream) {
  (void)in_sizes; (void)n_in; (void)out_size; (void)ws_size;
  const int* x = (const int*)d_in[0];
  const float* emb = (const float*)d_in[1];
  const float* WgFw = (const float*)d_in[2];
  const float* bgFw = (const float*)d_in[3];
  const float* WcFw = (const float*)d_in[4];
  const float* bcFw = (const float*)d_in[5];
  const float* WgBw = (const float*)d_in[6];
  const float* bgBw = (const float*)d_in[7];
  const float* WcBw = (const float*)d_in[8];
  const float* bcBw = (const float*)d_in[9];
  const float* WgU1 = (const float*)d_in[10];
  const float* bgU1 = (const float*)d_in[11];
  const float* WcU1 = (const float*)d_in[12];
  const float* bcU1 = (const float*)d_in[13];
  const float* WgU2 = (const float*)d_in[14];
  const float* bgU2 = (const float*)d_in[15];
  const float* WcU2 = (const float*)d_in[16];
  const float* bcU2 = (const float*)d_in[17];

  char* ws = (char*)d_ws;
  float* bufA = (float*)(ws + 0);                    // 39,321,600 (fw / u1 / - preacts)
  float* bufB = (float*)(ws + 39321600);             // 39,321,600 (bw / u2 preacts)
  unsigned short* ycatHi = (unsigned short*)(ws + 78643200);   // 13,107,200
  unsigned short* ycatLo = (unsigned short*)(ws + 91750400);   // 13,107,200
  // y1 planes overlay ycat region (ycat dead after u1 GEMM)
  unsigned short* y1Hi = (unsigned short*)(ws + 78643200);     // 6,553,600
  unsigned short* y1Lo = (unsigned short*)(ws + 85196800);     // 6,553,600
  unsigned short* wpFwHi = (unsigned short*)(ws + 104857600);  // 3,145,728 each
  unsigned short* wpFwLo = (unsigned short*)(ws + 108003328);
  unsigned short* wpBwHi = (unsigned short*)(ws + 111149056);
  unsigned short* wpBwLo = (unsigned short*)(ws + 114294784);
  unsigned short* wpU1Hi = (unsigned short*)(ws + 117440512);  // 4,718,592 each
  unsigned short* wpU1Lo = (unsigned short*)(ws + 122159104);  // ends 126,877,696
  // u2 pack overlays u1 region AFTER u1 scan completes
  unsigned short* wpU2Hi = (unsigned short*)(ws + 117440512);  // 3,145,728
  unsigned short* wpU2Lo = (unsigned short*)(ws + 120586240);
  unsigned short* hb = (unsigned short*)(ws + 126877696);      // 524,288
  unsigned* bars = (unsigned*)(ws + 127401984);                // 4,096

  unsigned short* hHiG = hb;
  unsigned short* hLoG = hb + 65536;
  unsigned short* rHiG = hb + 131072;
  unsigned short* rLoG = hb + 196608;

  float* out = (float*)d_out;
  float* st1 = out + (size_t)64 * TT * 512;
  float* st2 = st1 + 64 * 512;

  hipMemsetAsync(bars, 0, 4096, stream);

  // packs (full K): bidir ktTot=32, u1 ktTot=48
  pack_w_kernel<<<768, 256, 0, stream>>>(WgFw, WcFw, 1024, 512, 32, wpFwHi, wpFwLo);
  pack_w_kernel<<<768, 256, 0, stream>>>(WgBw, WcBw, 1024, 512, 32, wpBwHi, wpBwLo);
  pack_w_kernel<<<1152, 256, 0, stream>>>(WgU1, WcU1, 1024, 512, 48, wpU1Hi, wpU1Lo);

  // bidir input projections (embedding gather, split-bf16 MFMA)
  gemm_mfma<0><<<dim3(50, 12), 256, 0, stream>>>(
      x, emb, nullptr, nullptr, 0, wpFwHi, wpFwLo, 32, 16, bgFw, bcFw, bufA);
  gemm_mfma<0><<<dim3(50, 12), 256, 0, stream>>>(
      x, emb, nullptr, nullptr, 0, wpBwHi, wpBwLo, 32, 16, bgBw, bcBw, bufB);

  {  // bidirectional scan -> ycat planes
    const float *a0 = bufA, *a1 = bufB;
    const unsigned short *w0 = wpFwHi, *w1 = wpFwLo, *w2 = wpBwHi, *w3 = wpBwLo;
    int ktT = 32, ktH = 16;
    unsigned short *h0 = hHiG, *h1 = hLoG, *r0 = rHiG, *r1 = rLoG;
    unsigned* bp = bars;
    unsigned short *yh = ycatHi, *yl = ycatLo; int yld = 1024;
    float *on = nullptr, *sn = nullptr;
    void* args[] = {&a0, &a1, &w0, &w1, &w2, &w3, &ktT, &ktH, &h0, &h1, &r0, &r1,
                    &bp, &yh, &yl, &yld, &on, &sn};
    hipLaunchCooperativeKernel((const void*)gru_scan_kernel<16>, dim3(256), dim3(256),
                               args, 0, stream);
  }

  // u1 input projections: A = ycat planes [6400][1024]
  gemm_mfma<1><<<dim3(50, 12), 256, 0, stream>>>(
      nullptr, nullptr, ycatHi, ycatLo, 1024, wpU1Hi, wpU1Lo, 48, 32, bgU1, bcU1, bufA);

  {  // u1 scan -> y1 planes + st1
    const float *a0 = bufA, *a1 = nullptr;
    const unsigned short *w0 = wpU1Hi, *w1 = wpU1Lo, *w2 = nullptr, *w3 = nullptr;
    int ktT = 48, ktH = 32;
    unsigned short *h0 = hHiG, *h1 = hLoG, *r0 = rHiG, *r1 = rLoG;
    unsigned* bp = bars + 256;
    unsigned short *yh = y1Hi, *yl = y1Lo; int yld = 512;
    float *on = nullptr, *sn = st1;
    void* args[] = {&a0, &a1, &w0, &w1, &w2, &w3, &ktT, &ktH, &h0, &h1, &r0, &r1,
                    &bp, &yh, &yl, &yld, &on, &sn};
    hipLaunchCooperativeKernel((const void*)gru_scan_kernel<8>, dim3(256), dim3(256),
                               args, 0, stream);
  }

  // u2 pack (overlays u1 pack region; u1 weights dead after u1 scan)
  pack_w_kernel<<<768, 256, 0, stream>>>(WgU2, WcU2, 1024, 512, 32, wpU2Hi, wpU2Lo);

  // u2 input projections: A = y1 planes [6400][512]
  gemm_mfma<1><<<dim3(50, 12), 256, 0, stream>>>(
      nullptr, nullptr, y1Hi, y1Lo, 512, wpU2Hi, wpU2Lo, 32, 16, bgU2, bcU2, bufB);

  {  // u2 scan -> d_out (f32) + st2
    const float *a0 = bufB, *a1 = nullptr;
    const unsigned short *w0 = wpU2Hi, *w1 = wpU2Lo, *w2 = nullptr, *w3 = nullptr;
    int ktT = 32, ktH = 16;
    unsigned short *h0 = hHiG, *h1 = hLoG, *r0 = rHiG, *r1 = rLoG;
    unsigned* bp = bars + 512;
    unsigned short *yh = nullptr, *yl = nullptr; int yld = 0;
    float *on = out, *sn = st2;
    void* args[] = {&a0, &a1, &w0, &w1, &w2, &w3, &ktT, &ktH, &h0, &h1, &r0, &r1,
                    &bp, &yh, &yl, &yld, &on, &sn};
    hipLaunchCooperativeKernel((const void*)gru_scan_kernel<8>, dim3(256), dim3(256),
                               args, 0, stream);
  }
}